// Round 1
// baseline (1207.342 us; speedup 1.0000x reference)
//
#include <hip/hip_runtime.h>
#include <hip/hip_fp16.h>

#define TEMP_ 0.2
#define NITER 10

typedef _Float16 half_t;
struct __align__(8)  H4 { half_t h[4]; };
struct __align__(16) H8 { half_t h[8]; };

__device__ __forceinline__ float wsum(float v){
#pragma unroll
  for (int o = 32; o > 0; o >>= 1) v += __shfl_down(v, o, 64);
  return v;
}
__device__ __forceinline__ double wsumd(double v){
#pragma unroll
  for (int o = 32; o > 0; o >>= 1) v += __shfl_down(v, o, 64);
  return v;
}
__device__ __forceinline__ float wmin(float v){
#pragma unroll
  for (int o = 32; o > 0; o >>= 1) v = fminf(v, __shfl_down(v, o, 64));
  return v;
}

// order-preserving float<->uint map (works for negatives too)
__device__ __forceinline__ unsigned fenc(float f){
  unsigned u = __float_as_uint(f);
  return (u & 0x80000000u) ? ~u : (u | 0x80000000u);
}
__device__ __forceinline__ float fdec(unsigned u){
  return (u & 0x80000000u) ? __uint_as_float(u & 0x7FFFFFFFu) : __uint_as_float(~u);
}

__device__ __forceinline__ void get_stats(const double* __restrict__ sums,
                                          const unsigned* __restrict__ minbits,
                                          long long NM, float& cmin, float& kscale){
  double s  = sums[0];
  double ss = sums[1];
  double mean = s / (double)NM;
  double var  = (ss - mean * s) / (double)(NM - 1);   // ddof=1
  cmin  = fdec(*minbits);
  kscale = (float)(1.0 / (sqrt(var) * TEMP_));
}

// ---------------- init: zero scalars + colsum ----------------
__global__ void k_init(double* __restrict__ sums, double* __restrict__ Ssum,
                       unsigned* __restrict__ minbits, float* __restrict__ colsum, int M){
  int i = blockIdx.x * blockDim.x + threadIdx.x;
  if (i == 0){ sums[0] = 0.0; sums[1] = 0.0; *Ssum = 0.0; *minbits = 0xFFFFFFFFu; }
  if (i < M) colsum[i] = 0.f;
}

// ---------------- pass 1: min / sum / sumsq over cdist ----------------
__global__ __launch_bounds__(256) void k_reduce(const float* __restrict__ cd, long long n4,
                                                double* __restrict__ sums,
                                                unsigned* __restrict__ minbits){
  const float4* c4 = (const float4*)cd;
  long long i0 = (long long)blockIdx.x * blockDim.x + threadIdx.x;
  long long stride = (long long)gridDim.x * blockDim.x;
  double s = 0.0, ss = 0.0;
  float  fs = 0.f, fss = 0.f;
  float  mn = __int_as_float(0x7F800000); // +inf
  int cnt = 0;
  for (long long i = i0; i < n4; i += stride){
    float4 v = c4[i];
    mn = fminf(mn, fminf(fminf(v.x, v.y), fminf(v.z, v.w)));
    fs  += (v.x + v.y) + (v.z + v.w);
    fss += v.x*v.x + v.y*v.y + v.z*v.z + v.w*v.w;
    if (++cnt == 8){ s += fs; ss += fss; fs = 0.f; fss = 0.f; cnt = 0; } // fp32->fp64 every 32 elems
  }
  s += fs; ss += fss;
  s = wsumd(s); ss = wsumd(ss); mn = wmin(mn);
  __shared__ double lds[8];
  __shared__ float  ldm[4];
  int lane = threadIdx.x & 63, wid = threadIdx.x >> 6;
  if (lane == 0){ lds[wid] = s; lds[4 + wid] = ss; ldm[wid] = mn; }
  __syncthreads();
  if (threadIdx.x == 0){
    unsafeAtomicAdd(&sums[0], lds[0] + lds[1] + lds[2] + lds[3]);
    unsafeAtomicAdd(&sums[1], lds[4] + lds[5] + lds[6] + lds[7]);
    atomicMin(minbits, fenc(fminf(fminf(ldm[0], ldm[1]), fminf(ldm[2], ldm[3]))));
  }
}

// ---------------- pass 2: E=exp fp16, colsum (u=1), S ----------------
__global__ __launch_bounds__(256) void k_expcol(const float* __restrict__ cd, half_t* __restrict__ E,
                                                const double* __restrict__ sums,
                                                const unsigned* __restrict__ minbits,
                                                float* __restrict__ colsum, double* __restrict__ Ssum,
                                                int N, int M){
  float cmin, kscale;
  get_stats(sums, minbits, (long long)N * M, cmin, kscale);
  int c0 = blockIdx.x * 1024 + threadIdx.x * 4;
  int r0 = blockIdx.y * 64;
  float a0 = 0.f, a1 = 0.f, a2 = 0.f, a3 = 0.f;
#pragma unroll 4
  for (int r = 0; r < 64; ++r){
    long long idx = (long long)(r0 + r) * M + c0;
    float4 v = *(const float4*)(cd + idx);
    float e0 = __expf((cmin - v.x) * kscale);
    float e1 = __expf((cmin - v.y) * kscale);
    float e2 = __expf((cmin - v.z) * kscale);
    float e3 = __expf((cmin - v.w) * kscale);
    H4 o; o.h[0] = (half_t)e0; o.h[1] = (half_t)e1; o.h[2] = (half_t)e2; o.h[3] = (half_t)e3;
    *(H4*)(E + idx) = o;
    a0 += e0; a1 += e1; a2 += e2; a3 += e3;
  }
  unsafeAtomicAdd(&colsum[c0 + 0], a0);
  unsafeAtomicAdd(&colsum[c0 + 1], a1);
  unsafeAtomicAdd(&colsum[c0 + 2], a2);
  unsafeAtomicAdd(&colsum[c0 + 3], a3);
  float tot = wsum((a0 + a1) + (a2 + a3));
  __shared__ float lt[4];
  int lane = threadIdx.x & 63, wid = threadIdx.x >> 6;
  if (lane == 0) lt[wid] = tot;
  __syncthreads();
  if (threadIdx.x == 0) unsafeAtomicAdd(Ssum, (double)(lt[0] + lt[1] + lt[2] + lt[3]));
}

// ---------------- tiny: V_j = B_j * S / colsum_j ----------------
__global__ void k_v(const float* __restrict__ B, const float* __restrict__ colsum,
                    const double* __restrict__ Ssum, float* __restrict__ v, int M){
  int j = blockIdx.x * blockDim.x + threadIdx.x;
  if (j < M) v[j] = (float)((double)B[j] * (*Ssum) / (double)colsum[j]);
}

// ---------------- row pass: rowsum_i = sum_j E_ij v_j (8 rows/block) ----------------
__global__ __launch_bounds__(256) void k_row(const half_t* __restrict__ E, const float* __restrict__ v,
                                             float* __restrict__ rowsum, int M){
  int t = threadIdx.x;
  int r0 = blockIdx.x * 8;
  float vr[32];
#pragma unroll
  for (int k = 0; k < 4; ++k){
    int c = k * 2048 + t * 8;
    float4 a = *(const float4*)(v + c);
    float4 b = *(const float4*)(v + c + 4);
    vr[k*8+0] = a.x; vr[k*8+1] = a.y; vr[k*8+2] = a.z; vr[k*8+3] = a.w;
    vr[k*8+4] = b.x; vr[k*8+5] = b.y; vr[k*8+6] = b.z; vr[k*8+7] = b.w;
  }
  __shared__ float lds[4][8];
  int lane = t & 63, wid = t >> 6;
  for (int r = 0; r < 8; ++r){
    const half_t* Er = E + (long long)(r0 + r) * M;
    float p = 0.f;
#pragma unroll
    for (int k = 0; k < 4; ++k){
      H8 hh = *(const H8*)(Er + k * 2048 + t * 8);
      p += (float)hh.h[0]*vr[k*8+0] + (float)hh.h[1]*vr[k*8+1]
         + (float)hh.h[2]*vr[k*8+2] + (float)hh.h[3]*vr[k*8+3]
         + (float)hh.h[4]*vr[k*8+4] + (float)hh.h[5]*vr[k*8+5]
         + (float)hh.h[6]*vr[k*8+6] + (float)hh.h[7]*vr[k*8+7];
    }
    p = wsum(p);
    if (lane == 0) lds[wid][r] = p;
  }
  __syncthreads();
  if (t < 8) rowsum[r0 + t] = lds[0][t] + lds[1][t] + lds[2][t] + lds[3][t];
}

// ---------------- tiny: U_i = A_i * S / rowsum_i ; zero colsum ----------------
__global__ void k_u(const float* __restrict__ A, const float* __restrict__ rowsum,
                    const double* __restrict__ Ssum, float* __restrict__ u,
                    float* __restrict__ colsum, int N, int M){
  int i = blockIdx.x * blockDim.x + threadIdx.x;
  if (i < N) u[i] = (float)((double)A[i] * (*Ssum) / (double)rowsum[i]);
  if (i < M) colsum[i] = 0.f;
}

// ---------------- col pass: colsum_j = sum_i u_i E_ij ----------------
__global__ __launch_bounds__(256) void k_col(const half_t* __restrict__ E, const float* __restrict__ u,
                                             float* __restrict__ colsum, int M){
  int c0 = blockIdx.x * 1024 + threadIdx.x * 4;
  int r0 = blockIdx.y * 64;
  float a0 = 0.f, a1 = 0.f, a2 = 0.f, a3 = 0.f;
#pragma unroll 4
  for (int r = 0; r < 64; ++r){
    int row = r0 + r;
    float ur = u[row];
    H4 hh = *(const H4*)(E + (long long)row * M + c0);
    a0 += ur * (float)hh.h[0];
    a1 += ur * (float)hh.h[1];
    a2 += ur * (float)hh.h[2];
    a3 += ur * (float)hh.h[3];
  }
  unsafeAtomicAdd(&colsum[c0 + 0], a0);
  unsafeAtomicAdd(&colsum[c0 + 1], a1);
  unsafeAtomicAdd(&colsum[c0 + 2], a2);
  unsafeAtomicAdd(&colsum[c0 + 3], a3);
}

// ---------------- final: T = u_i * exp(..) * v_j / S  (recompute exp from cdist) ----------------
__global__ __launch_bounds__(256) void k_final(const float* __restrict__ cd,
                                               const float* __restrict__ u, const float* __restrict__ v,
                                               const double* __restrict__ sums,
                                               const unsigned* __restrict__ minbits,
                                               const double* __restrict__ Ssum,
                                               float* __restrict__ T, int N, int M){
  float cmin, kscale;
  get_stats(sums, minbits, (long long)N * M, cmin, kscale);
  float invS = (float)(1.0 / (*Ssum));
  int t = threadIdx.x;
  int r0 = blockIdx.x * 8;
  float vr[32];
#pragma unroll
  for (int k = 0; k < 4; ++k){
    int c = k * 2048 + t * 8;
    float4 a = *(const float4*)(v + c);
    float4 b = *(const float4*)(v + c + 4);
    vr[k*8+0] = a.x * invS; vr[k*8+1] = a.y * invS; vr[k*8+2] = a.z * invS; vr[k*8+3] = a.w * invS;
    vr[k*8+4] = b.x * invS; vr[k*8+5] = b.y * invS; vr[k*8+6] = b.z * invS; vr[k*8+7] = b.w * invS;
  }
  for (int r = 0; r < 8; ++r){
    int row = r0 + r;
    float ur = u[row];
#pragma unroll
    for (int k = 0; k < 4; ++k){
      long long idx = (long long)row * M + k * 2048 + t * 8;
      float4 a = *(const float4*)(cd + idx);
      float4 b = *(const float4*)(cd + idx + 4);
      float4 oa, ob;
      oa.x = ur * vr[k*8+0] * __expf((cmin - a.x) * kscale);
      oa.y = ur * vr[k*8+1] * __expf((cmin - a.y) * kscale);
      oa.z = ur * vr[k*8+2] * __expf((cmin - a.z) * kscale);
      oa.w = ur * vr[k*8+3] * __expf((cmin - a.w) * kscale);
      ob.x = ur * vr[k*8+4] * __expf((cmin - b.x) * kscale);
      ob.y = ur * vr[k*8+5] * __expf((cmin - b.y) * kscale);
      ob.z = ur * vr[k*8+6] * __expf((cmin - b.z) * kscale);
      ob.w = ur * vr[k*8+7] * __expf((cmin - b.w) * kscale);
      *(float4*)(T + idx) = oa;
      *(float4*)(T + idx + 4) = ob;
    }
  }
}

extern "C" void kernel_launch(void* const* d_in, const int* in_sizes, int n_in,
                              void* d_out, int out_size, void* d_ws, size_t ws_size,
                              hipStream_t stream){
  const float* cd = (const float*)d_in[0];
  const float* A  = (const float*)d_in[1];
  const float* B  = (const float*)d_in[2];
  int N = in_sizes[1];
  int M = in_sizes[2];
  float*  T = (float*)d_out;
  half_t* E = (half_t*)d_out;   // first N*M*2 bytes of d_out used as fp16 scratch for E

  char* ws = (char*)d_ws;
  double*   sums    = (double*)ws;          // [0]=sum, [1]=sumsq
  double*   Ssum    = (double*)(ws + 16);
  unsigned* minbits = (unsigned*)(ws + 24);
  float*    colsum  = (float*)(ws + 32);
  float*    rowsum  = colsum + M;
  float*    u       = rowsum + N;
  float*    v       = u + N;

  int mx = (N > M) ? N : M;
  long long n4 = (long long)N * M / 4;

  k_init<<<(mx + 255) / 256, 256, 0, stream>>>(sums, Ssum, minbits, colsum, M);
  k_reduce<<<2048, 256, 0, stream>>>(cd, n4, sums, minbits);
  k_expcol<<<dim3(M / 1024, N / 64), 256, 0, stream>>>(cd, E, sums, minbits, colsum, Ssum, N, M);

  for (int it = 0; it < NITER; ++it){
    if (it > 0) k_col<<<dim3(M / 1024, N / 64), 256, 0, stream>>>(E, u, colsum, M);
    k_v<<<(M + 255) / 256, 256, 0, stream>>>(B, colsum, Ssum, v, M);
    k_row<<<N / 8, 256, 0, stream>>>(E, v, rowsum, M);
    k_u<<<(mx + 255) / 256, 256, 0, stream>>>(A, rowsum, Ssum, u, colsum, N, M);
  }
  k_final<<<N / 8, 256, 0, stream>>>(cd, u, v, sums, minbits, Ssum, T, N, M);
}